// Round 11
// baseline (164.664 us; speedup 1.0000x reference)
//
#include <hip/hip_runtime.h>
#include <stdint.h>

#define L_SEQ 4096
#define NBATCH 2
#define HID 1024
#define HEADS 16
#define DH 64
#define Z_DIM 32
#define NBLK 64
#define NROWS 8192  // L_SEQ * NBATCH
#define NSPLIT 8    // head split-K factor (8 kblocks per split)

typedef float f32x4 __attribute__((ext_vector_type(4)));
typedef short short8 __attribute__((ext_vector_type(8)));
typedef uint32_t u32x4 __attribute__((ext_vector_type(4)));

typedef const uint32_t __attribute__((address_space(1))) *gas_ptr;
typedef uint32_t __attribute__((address_space(3))) *las_ptr;

__device__ __forceinline__ ushort f2bf(float f) {
  uint32_t u = __float_as_uint(f);
  uint32_t r = (u + 0x7FFFu + ((u >> 16) & 1u)) >> 16;  // RNE
  return (ushort)r;
}

// packed f32x2 -> bf16x2 (low = a, high = b), RNE
__device__ __forceinline__ uint32_t cvtpk(float a, float b) {
  uint32_t r;
  asm("v_cvt_pk_bf16_f32 %0, %1, %2" : "=v"(r) : "v"(a), "v"(b));
  return r;
}

__device__ __forceinline__ void gload_lds16(const void* g, void* l) {
  __builtin_amdgcn_global_load_lds((gas_ptr)g, (las_ptr)l, 16, 0, 0);
}

// ---------------- fused f32 -> bf16 conversion (query + 4 weights) --------
__global__ __launch_bounds__(256)
void cvt_multi(const float* __restrict__ s0, ushort* __restrict__ d0,
               const float* __restrict__ s1, ushort* __restrict__ d1,
               const float* __restrict__ s2, ushort* __restrict__ d2,
               const float* __restrict__ s3, ushort* __restrict__ d3,
               const float* __restrict__ s4, ushort* __restrict__ d4) {
  const int i = blockIdx.x * blockDim.x + threadIdx.x;
  const int NQ = NROWS * HID / 4;          // 2097152 float4s
  const float4* src; ushort4* dst; int off;
  if (i < NQ) {
    src = (const float4*)s0; dst = (ushort4*)d0; off = i;
  } else {
    const int j = i - NQ;
    const int r = j >> 18;                  // HID*HID/4 = 2^18 per weight
    off = j & ((1 << 18) - 1);
    src = (const float4*)(r == 0 ? s1 : r == 1 ? s2 : r == 2 ? s3 : s4);
    dst = (ushort4*)(r == 0 ? d1 : r == 1 ? d2 : r == 2 ? d3 : d4);
  }
  float4 v = src[off];
  ushort4 o;
  o.x = f2bf(v.x); o.y = f2bf(v.y); o.z = f2bf(v.z); o.w = f2bf(v.w);
  dst[off] = o;
}

// ---------------- bf16 NT GEMM: C = X @ W^T + bias ----------------
// 128x256 tile, BK=32, 4 waves (2Mx2N), wave-tile 64x128 (32 MFMA / 12
// ds_read per K-step). Depth-2 software pipeline: 2 LDS buffers (48 KB),
// counted vmcnt(6), raw barriers. 2-way-free XOR swizzle on 16B chunks.
// XCD bijective block swizzle. No launch_bounds VGPR cap (R8 spill lesson).
// FINAL=0: grid 768 = (64 by x 4 bx x 3 zid); Q/K/V epilogues via LDS
//          transpose staging, coalesced 16B bf16 stores.
// FINAL=1: grid 256; direct f32 row-major stores (d_out).
template <int FINAL>
__global__ __launch_bounds__(256)
void gemm_bt(const ushort* __restrict__ X,
             const ushort* __restrict__ W0, const ushort* __restrict__ W1,
             const ushort* __restrict__ W2,
             const float* __restrict__ b0, const float* __restrict__ b1,
             const float* __restrict__ b2,
             ushort* __restrict__ Qo, ushort* __restrict__ Ko,
             ushort* __restrict__ Vo, float* __restrict__ Fo) {
  const int tid = threadIdx.x;
  const int w = tid >> 6, l = tid & 63;
  const int lr = l & 15, lg = l >> 4;
  const int wr = w >> 1, wc = w & 1;

  // XCD-aware bijective block swizzle (total % 8 == 0)
  const int total = FINAL ? 256 : 768;
  const int per = total >> 3;
  const int f0 = blockIdx.x;
  const int nf = (f0 & 7) * per + (f0 >> 3);
  const int bx = nf & 3;
  const int by = (nf >> 2) & 63;
  const int zid = FINAL ? 0 : (nf >> 8);
  const int mbase = by * 128;
  const int nbase = bx * 256;

  const ushort* W = FINAL ? W0 : (zid == 0 ? W0 : (zid == 1 ? W1 : W2));
  const float*  B = FINAL ? b0 : (zid == 0 ? b0 : (zid == 1 ? b1 : b2));

  __shared__ ushort lds[2][12288];  // 48 KiB: per buf, lA (4096) | lB (8192)

  // loop-invariant swizzled k-chunk offset (shorts) within a 32-short row
  const int kch = (lg ^ ((lr >> 1) & 3)) << 3;

  f32x4 acc[4][8];
#pragma unroll
  for (int m = 0; m < 4; ++m)
#pragma unroll
    for (int n = 0; n < 8; ++n) acc[m][n] = (f32x4){0.f, 0.f, 0.f, 0.f};

  auto stage = [&](int k0, int buf) {
    // 1536 16B-chunks: A = 512 (128 rows x 4), B = 1024 (256 rows x 4)
#pragma unroll
    for (int s = 0; s < 6; ++s) {
      const int chunk = s * 256 + tid;
      void* dst = &lds[buf][(s * 256 + (tid & ~63)) * 8];
      if (s < 2) {
        const int row = chunk >> 2, cc = chunk & 3;
        const int scc = cc ^ ((row >> 1) & 3);  // pre-swizzled source
        gload_lds16(X + (size_t)(mbase + row) * HID + k0 + scc * 8, dst);
      } else {
        const int c2 = chunk - 512;
        const int row = c2 >> 2, cc = c2 & 3;
        const int scc = cc ^ ((row >> 1) & 3);
        gload_lds16(W + (size_t)(nbase + row) * HID + k0 + scc * 8, dst);
      }
    }
  };

  auto compute_tile = [&](const ushort* lA, const ushort* lB) {
    short8 af[4], bfr[8];
#pragma unroll
    for (int m = 0; m < 4; ++m)
      af[m] = *(const short8*)&lA[(wr * 64 + m * 16 + lr) * 32 + kch];
#pragma unroll
    for (int n = 0; n < 8; ++n)
      bfr[n] = *(const short8*)&lB[(wc * 128 + n * 16 + lr) * 32 + kch];
#pragma unroll
    for (int m = 0; m < 4; ++m)
#pragma unroll
      for (int n = 0; n < 8; ++n)
        acc[m][n] = __builtin_amdgcn_mfma_f32_16x16x32_bf16(af[m], bfr[n], acc[m][n], 0, 0, 0);
  };

  // ---- depth-2 pipelined K-loop (32 tiles of BK=32) ----
  stage(0, 0);
  stage(32, 1);
  for (int t = 0; t < 32; ++t) {
    if (t < 30) { asm volatile("s_waitcnt vmcnt(6)" ::: "memory"); }
    else        { asm volatile("s_waitcnt vmcnt(0)" ::: "memory"); }
    __builtin_amdgcn_s_barrier();           // tile t fully in LDS (all waves)
    __builtin_amdgcn_sched_barrier(0);
    compute_tile(&lds[t & 1][0], &lds[t & 1][4096]);
    __builtin_amdgcn_sched_barrier(0);
    asm volatile("s_waitcnt lgkmcnt(0)" ::: "memory");
    __builtin_amdgcn_s_barrier();           // all waves done reading buf t&1
    if (t < 30) stage((t + 2) * 32, t & 1); // overwrite freed buffer
  }

  if (FINAL) {
#pragma unroll
    for (int n = 0; n < 8; ++n) {
      const int col = nbase + wc * 128 + n * 16 + lr;
      const float bias = B[col];
#pragma unroll
      for (int m = 0; m < 4; ++m)
#pragma unroll
        for (int r = 0; r < 4; ++r) {
          const int row = mbase + wr * 64 + m * 16 + 4 * lg + r;
          Fo[(size_t)row * HID + col] = acc[m][n][r] + bias;
        }
    }
    return;
  }

  float biasn[8];
#pragma unroll
  for (int n = 0; n < 8; ++n) biasn[n] = B[nbase + wc * 128 + n * 16 + lr];
  ushort* st = &lds[0][0];

  if (zid == 2) {
    // ---- V: LDS transpose -> coalesced Vt[z][d][lseq] (16B stores) ----
    // slab [colL 0..127][ls 0..63], pitch 72 (18 KB), per (nb2, wc-half ch)
#pragma unroll
    for (int nb2 = 0; nb2 < 2; ++nb2) {
#pragma unroll
      for (int ch = 0; ch < 2; ++ch) {
        __syncthreads();
        if (wc == ch) {
#pragma unroll
          for (int m = 0; m < 4; ++m)
#pragma unroll
            for (int n = 0; n < 8; ++n)
#pragma unroll
              for (int rr = 0; rr < 2; ++rr) {
                const int r = nb2 + 2 * rr;
                st[(n * 16 + lr) * 72 + wr * 32 + m * 8 + 2 * lg + rr] =
                    f2bf(acc[m][n][r] + biasn[n]);
              }
        }
        __syncthreads();
#pragma unroll
        for (int it = 0; it < 4; ++it) {
          const int c = it * 256 + tid;          // 0..1023
          const int colI = c >> 3, ls0 = (c & 7) * 8;
          const short8 v = *(const short8*)&st[colI * 72 + ls0];
          const int fullcol = nbase + ch * 128 + colI;
          const int hd = fullcol >> 6, d = fullcol & 63;
          const int zz = nb2 * HEADS + hd;
          *(short8*)&Vo[((size_t)zz * DH + d) * L_SEQ + (mbase >> 1) + ls0] = v;
        }
      }
    }
  } else {
    // ---- Q/K: LDS stage -> coalesced Out[z][lseq][d] (16B stores) ----
    // slab [lseq-half 0..63][col 0..127], pitch 136 (17 KB)
    ushort* Out = (zid == 0) ? Qo : Ko;
    const float sc = (zid == 0) ? 0.125f : 1.f;
#pragma unroll
    for (int nbp = 0; nbp < 2; ++nbp) {
#pragma unroll
      for (int hh = 0; hh < 2; ++hh) {
        __syncthreads();
        if (wc == hh) {
#pragma unroll
          for (int m = 0; m < 4; ++m)
#pragma unroll
            for (int n = 0; n < 8; ++n)
#pragma unroll
              for (int rr = 0; rr < 2; ++rr) {
                const int r = nbp + 2 * rr;
                st[(wr * 32 + m * 8 + 2 * lg + rr) * 136 + n * 16 + lr] =
                    f2bf((acc[m][n][r] + biasn[n]) * sc);
              }
        }
        __syncthreads();
#pragma unroll
        for (int it = 0; it < 4; ++it) {
          const int c = it * 256 + tid;          // 0..1023
          const int lr2 = c >> 4, cc16 = c & 15;
          const int colv = cc16 * 8;             // 0..120
          const short8 v = *(const short8*)&st[lr2 * 136 + colv];
          const int hd2 = colv >> 6, d0 = colv & 63;
          const int zz = nbp * HEADS + (nbase >> 6) + hh * 2 + hd2;
          *(short8*)&Out[((size_t)zz * L_SEQ + (mbase >> 1) + lr2) * DH + d0] = v;
        }
      }
    }
  }
}

// ---------------- block-sparse attention (R7 version) ----------------
// Serial slots, single-buffer Kl/Vl LDS staging via global_load_lds +
// row-XOR swizzle, __syncthreads pairs; swapped-operand math:
// S = mfma(K, Q^T) so q = lane (lr). Lane-local softmax (15 fmax + 2 shfl);
// P bf16 via cvt_pk into per-wave u32 LDS slab (pitch 36); PV: O^T = mfma(V^T, P^T).
__global__ __launch_bounds__(256)
void attn_sparse(const ushort* __restrict__ Q, const ushort* __restrict__ K,
                 const ushort* __restrict__ Vt, const int* __restrict__ rnd,
                 ushort* __restrict__ O,
                 float* __restrict__ Pp, float* __restrict__ Mp,
                 float* __restrict__ Lp) {
  const int bid = blockIdx.x;
  int z, qb, split = 0;
  bool head;
  if (bid < Z_DIM * 62) {
    z = bid / 62; qb = bid % 62 + 2; head = false;
  } else {
    const int t = bid - Z_DIM * 62;          // 0..511
    z = t >> 4; qb = (t >> 3) & 1; split = t & 7; head = true;
  }
  const int tid = threadIdx.x;
  const int w = tid >> 6, l = tid & 63;
  const int lr = l & 15, lg = l >> 4;

  __shared__ ushort Kl[64 * 64];
  __shared__ ushort Vl[64 * 64];
  __shared__ uint32_t P2[4][16 * 36];  // per-wave P^T: [q=lr][kp], pitch 36 u32

  // B-operand Q^T fragments: lane holds Q[q = lr][d = lg*8 + j]
  const ushort* Qrow = Q + ((size_t)z * L_SEQ + qb * 64 + w * 16 + lr) * DH;
  const short8 bq0 = *(const short8*)(Qrow + lg * 8);
  const short8 bq1 = *(const short8*)(Qrow + 32 + lg * 8);

  float m = -1e30f, lsum = 0.f;
  f32x4 accO[4];  // accO[td][r] = O[q=lr][d = td*16 + 4*lg + r]
#pragma unroll
  for (int td = 0; td < 4; ++td) accO[td] = (f32x4){0.f, 0.f, 0.f, 0.f};

  const int nslot = head ? 8 : 7;
  int sk[3] = {0, 0, 0}, sv[3] = {0, 0, 0}, rk0 = 0, rk1 = 0;
  if (!head) {
    const int i = qb - 2;
    rk0 = rnd[2 * i]; rk1 = rnd[2 * i + 1];
    if (qb < NBLK - 1) {
      sk[0] = qb - 1; sk[1] = qb; sk[2] = qb + 1;
      sv[0] = qb - 1; sv[1] = qb; sv[2] = qb + 1;
    } else {  // bottom row: K = {ZERO, 62, 63}, V = {62, 63, ZERO}
      sk[0] = -1; sk[1] = NBLK - 2; sk[2] = NBLK - 1;
      sv[0] = NBLK - 2; sv[1] = NBLK - 1; sv[2] = -1;
    }
  }

  for (int slot = 0; slot < nslot; ++slot) {
    int ki, vi;
    if (head) { ki = split * 8 + slot; vi = ki; }
    else if (slot < 2) { ki = slot; vi = slot; }
    else if (slot < 5) { ki = sk[slot - 2]; vi = sv[slot - 2]; }
    else { ki = (slot == 5) ? rk0 : rk1; vi = ki; }

    if (slot) __syncthreads();  // all waves done reading Kl/Vl
#pragma unroll
    for (int s = 0; s < 2; ++s) {
      const int chunk = s * 256 + tid;
      const int row = chunk >> 3, cc = chunk & 7;
      const int scc = cc ^ (row & 7);  // pre-swizzled global source
      if (ki >= 0)
        gload_lds16(K + ((size_t)z * L_SEQ + ki * 64 + row) * DH + scc * 8,
                    &Kl[(s * 256 + (tid & ~63)) * 8]);
      if (vi >= 0)
        gload_lds16(Vt + ((size_t)z * DH + row) * L_SEQ + vi * 64 + scc * 8,
                    &Vl[(s * 256 + (tid & ~63)) * 8]);
    }
    __syncthreads();

    // ---- QK^T (swapped): sc[t][r] = S[key = t*16+4*lg+r][q = lr] ----
    f32x4 sc[4];
    if (ki >= 0) {
#pragma unroll
      for (int t = 0; t < 4; ++t) {
        const int row = t * 16 + lr;
        const short8 a0 = *(const short8*)&Kl[row * 64 + ((lg ^ (row & 7)) << 3)];
        const short8 a1 = *(const short8*)&Kl[row * 64 + (((4 + lg) ^ (row & 7)) << 3)];
        f32x4 zz = (f32x4){0.f, 0.f, 0.f, 0.f};
        sc[t] = __builtin_amdgcn_mfma_f32_16x16x32_bf16(a0, bq0, zz, 0, 0, 0);
        sc[t] = __builtin_amdgcn_mfma_f32_16x16x32_bf16(a1, bq1, sc[t], 0, 0, 0);
      }
    } else {
#pragma unroll
      for (int t = 0; t < 4; ++t) sc[t] = (f32x4){0.f, 0.f, 0.f, 0.f};
    }

    // ---- online softmax over keys (16 regs x 4 lg-groups) ----
    float sm = sc[0][0];
#pragma unroll
    for (int t = 0; t < 4; ++t)
#pragma unroll
      for (int r = 0; r < 4; ++r) sm = fmaxf(sm, sc[t][r]);
    sm = fmaxf(sm, __shfl_xor(sm, 16));
    sm = fmaxf(sm, __shfl_xor(sm, 32));
    const float mn = fmaxf(m, sm);
    const float scale = __expf(m - mn);
    m = mn;
    lsum *= scale;
#pragma unroll
    for (int td = 0; td < 4; ++td)
#pragma unroll
      for (int r = 0; r < 4; ++r) accO[td][r] *= scale;
    float psum = 0.f;
#pragma unroll
    for (int t = 0; t < 4; ++t)
#pragma unroll
      for (int r = 0; r < 4; ++r) {
        const float p = __expf(sc[t][r] - mn);
        sc[t][r] = p;
        psum += p;
      }
    psum += __shfl_xor(psum, 16);
    psum += __shfl_xor(psum, 32);
    lsum += psum;

    if (vi >= 0) {
      // P -> bf16x2 u32s -> per-wave LDS [q=lr][kp], kp = key/2
      uint32_t* Pq = &P2[w][0];
#pragma unroll
      for (int t = 0; t < 4; ++t) {
        Pq[lr * 36 + t * 8 + 2 * lg + 0] = cvtpk(sc[t][0], sc[t][1]);
        Pq[lr * 36 + t * 8 + 2 * lg + 1] = cvtpk(sc[t][2], sc[t][3]);
      }
      // B-frags: lane holds P^T[key = f*32 + lg*8 + j][q = lr]
      union { u32x4 u; short8 s8; } pb0, pb1;
      pb0.u = *(const u32x4*)&Pq[lr * 36 + lg * 4];
      pb1.u = *(const u32x4*)&Pq[lr * 36 + 16 + lg * 4];
#pragma unroll
      for (int td = 0; td < 4; ++td) {
        const int row = td * 16 + lr;
        const short8 av0 = *(const short8*)&Vl[row * 64 + ((lg ^ (row & 7)) << 3)];
        const short8 av1 = *(const short8*)&Vl[row * 64 + (((4 + lg) ^ (row & 7)) << 3)];
        accO[td] = __builtin_amdgcn_mfma_f32_16x16x32_bf16(av0, pb0.s8, accO[td], 0, 0, 0);
        accO[td] = __builtin_amdgcn_mfma_f32_16x16x32_bf16(av1, pb1.s8, accO[td], 0, 0, 0);
      }
    }
  }

  if (!head) {
    const float inv = 1.f / lsum;
    const int nb = z >> 4, hd = z & 15;
    const size_t rowbase =
        ((size_t)(qb * 64 + w * 16 + lr) * NBATCH + nb) * HID + hd * 64;
#pragma unroll
    for (int td = 0; td < 4; ++td) {
      uint2 o;
      o.x = cvtpk(accO[td][0] * inv, accO[td][1] * inv);
      o.y = cvtpk(accO[td][2] * inv, accO[td][3] * inv);
      *(uint2*)&O[rowbase + td * 16 + 4 * lg] = o;
    }
  } else {
    const int hbase = (qb * Z_DIM + z) * NSPLIT + split;
    const size_t prow = (size_t)hbase * 64 + w * 16 + lr;
#pragma unroll
    for (int td = 0; td < 4; ++td)
      *(f32x4*)&Pp[prow * 64 + td * 16 + 4 * lg] = accO[td];
    if (l < 16) {
      Mp[hbase * 64 + w * 16 + lr] = m;
      Lp[hbase * 64 + w * 16 + lr] = lsum;
    }
  }
}

// ---------------- combine head split-K partials ----------------
__global__ __launch_bounds__(256)
void head_reduce(const float* __restrict__ Pp, const float* __restrict__ Mp,
                 const float* __restrict__ Lp, ushort* __restrict__ O) {
  const int z = blockIdx.x >> 1, qb = blockIdx.x & 1;
  const int tid = threadIdx.x;
  const int row = tid >> 2, cg = tid & 3;
  const int base = (qb * Z_DIM + z) * NSPLIT;

  float mm[NSPLIT], wgt[NSPLIT];
  float mx = -1e30f;
#pragma unroll
  for (int s = 0; s < NSPLIT; ++s) {
    mm[s] = Mp[(base + s) * 64 + row];
    mx = fmaxf(mx, mm[s]);
  }
  float denom = 0.f;
#pragma unroll
  for (int s = 0; s < NSPLIT; ++s) {
    wgt[s] = __expf(mm[s] - mx);
    denom += Lp[(base + s) * 64 + row] * wgt[s];
  }
  const float inv = 1.f / denom;

  const int nb = z >> 4, hd = z & 15;
  const int lseq = qb * 64 + row;
#pragma unroll
  for (int c = 0; c < 16; ++c) {
    const int col = cg * 16 + c;
    float acc = 0.f;
#pragma unroll
    for (int s = 0; s < NSPLIT; ++s)
      acc += Pp[((size_t)(base + s) * 64 + row) * 64 + col] * wgt[s];
    O[((size_t)lseq * NBATCH + nb) * HID + hd * 64 + col] = f2bf(acc * inv);
  }
}

extern "C" void kernel_launch(void* const* d_in, const int* in_sizes, int n_in,
                              void* d_out, int out_size, void* d_ws, size_t ws_size,
                              hipStream_t stream) {
  (void)in_sizes; (void)n_in; (void)out_size; (void)ws_size;
  const float* query    = (const float*)d_in[0];
  const float* q_proj   = (const float*)d_in[1];
  const float* q_bias   = (const float*)d_in[2];
  const float* k_proj   = (const float*)d_in[3];
  const float* k_bias   = (const float*)d_in[4];
  const float* v_proj   = (const float*)d_in[5];
  const float* v_bias   = (const float*)d_in[6];
  const float* out_proj = (const float*)d_in[7];
  const float* out_bias = (const float*)d_in[8];
  const int*   rnd      = (const int*)d_in[9];

  ushort* Xb  = (ushort*)d_ws;                         // [8192][1024] bf16
  ushort* Wq  = Xb + (size_t)NROWS * HID;
  ushort* Wk  = Wq + (size_t)HID * HID;
  ushort* Wv  = Wk + (size_t)HID * HID;
  ushort* Wo  = Wv + (size_t)HID * HID;
  ushort* Qb  = Wo + (size_t)HID * HID;                // [Z][L][64]
  ushort* Kb  = Qb + (size_t)Z_DIM * L_SEQ * DH;       // [Z][L][64]
  ushort* Vtb = Kb + (size_t)Z_DIM * L_SEQ * DH;       // [Z][64][L]
  float*  Pp  = (float*)(Vtb + (size_t)Z_DIM * DH * L_SEQ);  // head partials
  float*  Mp  = Pp + (size_t)2 * Z_DIM * NSPLIT * 64 * 64;
  float*  Lp  = Mp + (size_t)2 * Z_DIM * NSPLIT * 64;
  ushort* Ob  = Xb;  // alias: X dead after QKV GEMM, O written by attn
  float*  Fo  = (float*)d_out;

  cvt_multi<<<(NROWS * HID / 4 + 4 * HID * HID / 4) / 256, 256, 0, stream>>>(
      query, Xb, q_proj, Wq, k_proj, Wk, v_proj, Wv, out_proj, Wo);

  gemm_bt<0><<<768, 256, 0, stream>>>(
      Xb, Wq, Wk, Wv, q_bias, k_bias, v_bias, Qb, Kb, Vtb, nullptr);

  attn_sparse<<<Z_DIM * 62 + 2 * Z_DIM * NSPLIT, 256, 0, stream>>>(
      Qb, Kb, Vtb, rnd, Ob, Pp, Mp, Lp);

  head_reduce<<<2 * Z_DIM, 256, 0, stream>>>(Pp, Mp, Lp, Ob);

  gemm_bt<1><<<256, 256, 0, stream>>>(
      Ob, Wo, nullptr, nullptr, out_bias, nullptr, nullptr,
      nullptr, nullptr, nullptr, Fo);
}

// Round 12
// 156.518 us; speedup vs baseline: 1.0520x; 1.0520x over previous
//
#include <hip/hip_runtime.h>
#include <stdint.h>

#define L_SEQ 4096
#define NBATCH 2
#define HID 1024
#define HEADS 16
#define DH 64
#define Z_DIM 32
#define NBLK 64
#define NROWS 8192  // L_SEQ * NBATCH
#define NSPLIT 8    // head split-K factor (8 kblocks per split)

typedef float f32x4 __attribute__((ext_vector_type(4)));
typedef short short8 __attribute__((ext_vector_type(8)));
typedef uint32_t u32x4 __attribute__((ext_vector_type(4)));

typedef const uint32_t __attribute__((address_space(1))) *gas_ptr;
typedef uint32_t __attribute__((address_space(3))) *las_ptr;

__device__ __forceinline__ ushort f2bf(float f) {
  uint32_t u = __float_as_uint(f);
  uint32_t r = (u + 0x7FFFu + ((u >> 16) & 1u)) >> 16;  // RNE
  return (ushort)r;
}

// packed f32x2 -> bf16x2 (low = a, high = b), RNE
__device__ __forceinline__ uint32_t cvtpk(float a, float b) {
  uint32_t r;
  asm("v_cvt_pk_bf16_f32 %0, %1, %2" : "=v"(r) : "v"(a), "v"(b));
  return r;
}

__device__ __forceinline__ void gload_lds16(const void* g, void* l) {
  __builtin_amdgcn_global_load_lds((gas_ptr)g, (las_ptr)l, 16, 0, 0);
}

// ---------------- fused f32 -> bf16 conversion (query + 4 weights) --------
__global__ __launch_bounds__(256)
void cvt_multi(const float* __restrict__ s0, ushort* __restrict__ d0,
               const float* __restrict__ s1, ushort* __restrict__ d1,
               const float* __restrict__ s2, ushort* __restrict__ d2,
               const float* __restrict__ s3, ushort* __restrict__ d3,
               const float* __restrict__ s4, ushort* __restrict__ d4) {
  const int i = blockIdx.x * blockDim.x + threadIdx.x;
  const int NQ = NROWS * HID / 4;          // 2097152 float4s
  const float4* src; ushort4* dst; int off;
  if (i < NQ) {
    src = (const float4*)s0; dst = (ushort4*)d0; off = i;
  } else {
    const int j = i - NQ;
    const int r = j >> 18;                  // HID*HID/4 = 2^18 per weight
    off = j & ((1 << 18) - 1);
    src = (const float4*)(r == 0 ? s1 : r == 1 ? s2 : r == 2 ? s3 : s4);
    dst = (ushort4*)(r == 0 ? d1 : r == 1 ? d2 : r == 2 ? d3 : d4);
  }
  float4 v = src[off];
  ushort4 o;
  o.x = f2bf(v.x); o.y = f2bf(v.y); o.z = f2bf(v.z); o.w = f2bf(v.w);
  dst[off] = o;
}

// ---------------- bf16 NT GEMM: C = X @ W^T + bias ----------------
// 128x128 tile, BK=32, 4 waves (2x2), 16x16x32 MFMA.
// THREE LDS buffers (48 KB), depth-2 prefetch, counted vmcnt(4), and a
// SINGLE barrier per K-step: at the top-of-iter barrier every wave's
// ds_reads of buf (t-1)%3 have completed (compiler lgkmcnt before the
// consuming MFMAs), so stage(t+2) -> buf (t-1)%3 after compute is safe.
// 2-way-free XOR swizzle c ^= (row>>1)&3 on 16B chunks. XCD block swizzle.
// No launch_bounds VGPR cap (R8 spill lesson). 128x256 tile regressed (R10:
// 1 WG/CU). FINAL=0: Q/K/V epilogues via LDS transpose staging.
template <int FINAL>
__global__ __launch_bounds__(256)
void gemm_bt(const ushort* __restrict__ X,
             const ushort* __restrict__ W0, const ushort* __restrict__ W1,
             const ushort* __restrict__ W2,
             const float* __restrict__ b0, const float* __restrict__ b1,
             const float* __restrict__ b2,
             ushort* __restrict__ Qo, ushort* __restrict__ Ko,
             ushort* __restrict__ Vo, float* __restrict__ Fo) {
  const int tid = threadIdx.x;
  const int w = tid >> 6, l = tid & 63;
  const int lr = l & 15, lg = l >> 4;
  const int wr = w >> 1, wc = w & 1;

  // XCD-aware bijective block swizzle (total % 8 == 0)
  const int total = FINAL ? 512 : 1536;
  const int per = total >> 3;
  const int f0 = blockIdx.x;
  const int nf = (f0 & 7) * per + (f0 >> 3);
  const int bx = nf & 7;
  const int by = (nf >> 3) & 63;
  const int zid = FINAL ? 0 : (nf >> 9);
  const int mbase = by * 128;
  const int nbase = bx * 128;

  const ushort* W = FINAL ? W0 : (zid == 0 ? W0 : (zid == 1 ? W1 : W2));
  const float*  B = FINAL ? b0 : (zid == 0 ? b0 : (zid == 1 ? b1 : b2));

  __shared__ ushort lds[3][8192];  // 48 KiB: per buf, lA (4096) | lB (4096)

  // loop-invariant swizzled k-chunk offset (shorts) within a 32-short row
  const int kch = (lg ^ ((lr >> 1) & 3)) << 3;

  f32x4 acc[4][4];
#pragma unroll
  for (int m = 0; m < 4; ++m)
#pragma unroll
    for (int n = 0; n < 4; ++n) acc[m][n] = (f32x4){0.f, 0.f, 0.f, 0.f};

  auto stage = [&](int k0, int buf) {
#pragma unroll
    for (int s = 0; s < 2; ++s) {
      const int chunk = s * 256 + tid;        // 0..511, 16B chunks
      const int row = chunk >> 2, cc = chunk & 3;
      const int scc = cc ^ ((row >> 1) & 3);  // pre-swizzled global source
      gload_lds16(X + (size_t)(mbase + row) * HID + k0 + scc * 8,
                  &lds[buf][(s * 256 + (tid & ~63)) * 8]);
      gload_lds16(W + (size_t)(nbase + row) * HID + k0 + scc * 8,
                  &lds[buf][4096 + (s * 256 + (tid & ~63)) * 8]);
    }
  };

  auto compute_tile = [&](const ushort* lA, const ushort* lB) {
    short8 af[4], bfr[4];
#pragma unroll
    for (int m = 0; m < 4; ++m)
      af[m] = *(const short8*)&lA[(wr * 64 + m * 16 + lr) * 32 + kch];
#pragma unroll
    for (int n = 0; n < 4; ++n)
      bfr[n] = *(const short8*)&lB[(wc * 64 + n * 16 + lr) * 32 + kch];
#pragma unroll
    for (int m = 0; m < 4; ++m)
#pragma unroll
      for (int n = 0; n < 4; ++n)
        acc[m][n] = __builtin_amdgcn_mfma_f32_16x16x32_bf16(af[m], bfr[n], acc[m][n], 0, 0, 0);
  };

  // ---- 3-buffer single-barrier K-loop (32 tiles of BK=32) ----
  stage(0, 0);
  stage(32, 1);
  for (int t = 0; t < 32; ++t) {
    if (t < 30) { asm volatile("s_waitcnt vmcnt(4)" ::: "memory"); }
    else        { asm volatile("s_waitcnt vmcnt(0)" ::: "memory"); }
    __builtin_amdgcn_s_barrier();  // stage(t) visible; buf (t-1)%3 free
    __builtin_amdgcn_sched_barrier(0);
    const int b = t % 3;
    compute_tile(&lds[b][0], &lds[b][4096]);
    if (t < 30) stage((t + 2) * 32, (t + 2) % 3);  // overwrite (t-1)%3
  }

  if (FINAL) {
#pragma unroll
    for (int n = 0; n < 4; ++n) {
      const int col = nbase + wc * 64 + n * 16 + lr;
      const float bias = B[col];
#pragma unroll
      for (int m = 0; m < 4; ++m)
#pragma unroll
        for (int r = 0; r < 4; ++r) {
          const int row = mbase + wr * 64 + m * 16 + 4 * lg + r;
          Fo[(size_t)row * HID + col] = acc[m][n][r] + bias;
        }
    }
    return;
  }

  float biasn[4];
#pragma unroll
  for (int n = 0; n < 4; ++n) biasn[n] = B[nbase + wc * 64 + n * 16 + lr];
  ushort* st = &lds[0][0];

  if (zid == 2) {
    // ---- V: LDS transpose -> coalesced Vt[z][d][lseq] (16B stores) ----
#pragma unroll
    for (int nb2 = 0; nb2 < 2; ++nb2) {
#pragma unroll
      for (int ch = 0; ch < 2; ++ch) {
        __syncthreads();
        if (wc == ch) {
#pragma unroll
          for (int m = 0; m < 4; ++m)
#pragma unroll
            for (int n = 0; n < 4; ++n)
#pragma unroll
              for (int rr = 0; rr < 2; ++rr) {
                const int r = nb2 + 2 * rr;
                st[(n * 16 + lr) * 72 + wr * 32 + m * 8 + 2 * lg + rr] =
                    f2bf(acc[m][n][r] + biasn[n]);
              }
        }
        __syncthreads();
        const int zz = nb2 * HEADS + (nbase >> 6) + ch;
#pragma unroll
        for (int it = 0; it < 2; ++it) {
          const int c = it * 256 + tid;          // 0..511
          const int colI = c >> 3, ls0 = (c & 7) * 8;
          const short8 v = *(const short8*)&st[colI * 72 + ls0];
          *(short8*)&Vo[((size_t)zz * DH + colI) * L_SEQ + (mbase >> 1) + ls0] = v;
        }
      }
    }
  } else {
    // ---- Q/K: LDS stage -> coalesced Out[z][lseq][d] (16B stores) ----
    ushort* Out = (zid == 0) ? Qo : Ko;
    const float sc = (zid == 0) ? 0.125f : 1.f;
#pragma unroll
    for (int nbp = 0; nbp < 2; ++nbp) {
#pragma unroll
      for (int hh = 0; hh < 2; ++hh) {
        __syncthreads();
        if (wc == hh) {
#pragma unroll
          for (int m = 0; m < 4; ++m)
#pragma unroll
            for (int n = 0; n < 4; ++n)
#pragma unroll
              for (int rr = 0; rr < 2; ++rr) {
                const int r = nbp + 2 * rr;
                st[(wr * 32 + m * 8 + 2 * lg + rr) * 72 + n * 16 + lr] =
                    f2bf((acc[m][n][r] + biasn[n]) * sc);
              }
        }
        __syncthreads();
        const int zz = nbp * HEADS + (nbase >> 6) + hh;
#pragma unroll
        for (int it = 0; it < 2; ++it) {
          const int c = it * 256 + tid;          // 0..511
          const int lr2 = c >> 3, cc8 = c & 7;
          const short8 v = *(const short8*)&st[lr2 * 72 + cc8 * 8];
          *(short8*)&Out[((size_t)zz * L_SEQ + (mbase >> 1) + lr2) * DH + cc8 * 8] = v;
        }
      }
    }
  }
}

// ---------------- block-sparse attention (R7 version) ----------------
// Serial slots, single-buffer Kl/Vl LDS staging via global_load_lds +
// row-XOR swizzle, __syncthreads pairs; swapped-operand math:
// S = mfma(K, Q^T) so q = lane (lr). Lane-local softmax (15 fmax + 2 shfl);
// P bf16 via cvt_pk into per-wave u32 LDS slab (pitch 36); PV: O^T = mfma(V^T, P^T).
__global__ __launch_bounds__(256)
void attn_sparse(const ushort* __restrict__ Q, const ushort* __restrict__ K,
                 const ushort* __restrict__ Vt, const int* __restrict__ rnd,
                 ushort* __restrict__ O,
                 float* __restrict__ Pp, float* __restrict__ Mp,
                 float* __restrict__ Lp) {
  const int bid = blockIdx.x;
  int z, qb, split = 0;
  bool head;
  if (bid < Z_DIM * 62) {
    z = bid / 62; qb = bid % 62 + 2; head = false;
  } else {
    const int t = bid - Z_DIM * 62;          // 0..511
    z = t >> 4; qb = (t >> 3) & 1; split = t & 7; head = true;
  }
  const int tid = threadIdx.x;
  const int w = tid >> 6, l = tid & 63;
  const int lr = l & 15, lg = l >> 4;

  __shared__ ushort Kl[64 * 64];
  __shared__ ushort Vl[64 * 64];
  __shared__ uint32_t P2[4][16 * 36];  // per-wave P^T: [q=lr][kp], pitch 36 u32

  // B-operand Q^T fragments: lane holds Q[q = lr][d = lg*8 + j]
  const ushort* Qrow = Q + ((size_t)z * L_SEQ + qb * 64 + w * 16 + lr) * DH;
  const short8 bq0 = *(const short8*)(Qrow + lg * 8);
  const short8 bq1 = *(const short8*)(Qrow + 32 + lg * 8);

  float m = -1e30f, lsum = 0.f;
  f32x4 accO[4];  // accO[td][r] = O[q=lr][d = td*16 + 4*lg + r]
#pragma unroll
  for (int td = 0; td < 4; ++td) accO[td] = (f32x4){0.f, 0.f, 0.f, 0.f};

  const int nslot = head ? 8 : 7;
  int sk[3] = {0, 0, 0}, sv[3] = {0, 0, 0}, rk0 = 0, rk1 = 0;
  if (!head) {
    const int i = qb - 2;
    rk0 = rnd[2 * i]; rk1 = rnd[2 * i + 1];
    if (qb < NBLK - 1) {
      sk[0] = qb - 1; sk[1] = qb; sk[2] = qb + 1;
      sv[0] = qb - 1; sv[1] = qb; sv[2] = qb + 1;
    } else {  // bottom row: K = {ZERO, 62, 63}, V = {62, 63, ZERO}
      sk[0] = -1; sk[1] = NBLK - 2; sk[2] = NBLK - 1;
      sv[0] = NBLK - 2; sv[1] = NBLK - 1; sv[2] = -1;
    }
  }

  for (int slot = 0; slot < nslot; ++slot) {
    int ki, vi;
    if (head) { ki = split * 8 + slot; vi = ki; }
    else if (slot < 2) { ki = slot; vi = slot; }
    else if (slot < 5) { ki = sk[slot - 2]; vi = sv[slot - 2]; }
    else { ki = (slot == 5) ? rk0 : rk1; vi = ki; }

    if (slot) __syncthreads();  // all waves done reading Kl/Vl
#pragma unroll
    for (int s = 0; s < 2; ++s) {
      const int chunk = s * 256 + tid;
      const int row = chunk >> 3, cc = chunk & 7;
      const int scc = cc ^ (row & 7);  // pre-swizzled global source
      if (ki >= 0)
        gload_lds16(K + ((size_t)z * L_SEQ + ki * 64 + row) * DH + scc * 8,
                    &Kl[(s * 256 + (tid & ~63)) * 8]);
      if (vi >= 0)
        gload_lds16(Vt + ((size_t)z * DH + row) * L_SEQ + vi * 64 + scc * 8,
                    &Vl[(s * 256 + (tid & ~63)) * 8]);
    }
    __syncthreads();

    // ---- QK^T (swapped): sc[t][r] = S[key = t*16+4*lg+r][q = lr] ----
    f32x4 sc[4];
    if (ki >= 0) {
#pragma unroll
      for (int t = 0; t < 4; ++t) {
        const int row = t * 16 + lr;
        const short8 a0 = *(const short8*)&Kl[row * 64 + ((lg ^ (row & 7)) << 3)];
        const short8 a1 = *(const short8*)&Kl[row * 64 + (((4 + lg) ^ (row & 7)) << 3)];
        f32x4 zz = (f32x4){0.f, 0.f, 0.f, 0.f};
        sc[t] = __builtin_amdgcn_mfma_f32_16x16x32_bf16(a0, bq0, zz, 0, 0, 0);
        sc[t] = __builtin_amdgcn_mfma_f32_16x16x32_bf16(a1, bq1, sc[t], 0, 0, 0);
      }
    } else {
#pragma unroll
      for (int t = 0; t < 4; ++t) sc[t] = (f32x4){0.f, 0.f, 0.f, 0.f};
    }

    // ---- online softmax over keys (16 regs x 4 lg-groups) ----
    float sm = sc[0][0];
#pragma unroll
    for (int t = 0; t < 4; ++t)
#pragma unroll
      for (int r = 0; r < 4; ++r) sm = fmaxf(sm, sc[t][r]);
    sm = fmaxf(sm, __shfl_xor(sm, 16));
    sm = fmaxf(sm, __shfl_xor(sm, 32));
    const float mn = fmaxf(m, sm);
    const float scale = __expf(m - mn);
    m = mn;
    lsum *= scale;
#pragma unroll
    for (int td = 0; td < 4; ++td)
#pragma unroll
      for (int r = 0; r < 4; ++r) accO[td][r] *= scale;
    float psum = 0.f;
#pragma unroll
    for (int t = 0; t < 4; ++t)
#pragma unroll
      for (int r = 0; r < 4; ++r) {
        const float p = __expf(sc[t][r] - mn);
        sc[t][r] = p;
        psum += p;
      }
    psum += __shfl_xor(psum, 16);
    psum += __shfl_xor(psum, 32);
    lsum += psum;

    if (vi >= 0) {
      // P -> bf16x2 u32s -> per-wave LDS [q=lr][kp], kp = key/2
      uint32_t* Pq = &P2[w][0];
#pragma unroll
      for (int t = 0; t < 4; ++t) {
        Pq[lr * 36 + t * 8 + 2 * lg + 0] = cvtpk(sc[t][0], sc[t][1]);
        Pq[lr * 36 + t * 8 + 2 * lg + 1] = cvtpk(sc[t][2], sc[t][3]);
      }
      // B-frags: lane holds P^T[key = f*32 + lg*8 + j][q = lr]
      union { u32x4 u; short8 s8; } pb0, pb1;
      pb0.u = *(const u32x4*)&Pq[lr * 36 + lg * 4];
      pb1.u = *(const u32x4*)&Pq[lr * 36 + 16 + lg * 4];
#pragma unroll
      for (int td = 0; td < 4; ++td) {
        const int row = td * 16 + lr;
        const short8 av0 = *(const short8*)&Vl[row * 64 + ((lg ^ (row & 7)) << 3)];
        const short8 av1 = *(const short8*)&Vl[row * 64 + (((4 + lg) ^ (row & 7)) << 3)];
        accO[td] = __builtin_amdgcn_mfma_f32_16x16x32_bf16(av0, pb0.s8, accO[td], 0, 0, 0);
        accO[td] = __builtin_amdgcn_mfma_f32_16x16x32_bf16(av1, pb1.s8, accO[td], 0, 0, 0);
      }
    }
  }

  if (!head) {
    const float inv = 1.f / lsum;
    const int nb = z >> 4, hd = z & 15;
    const size_t rowbase =
        ((size_t)(qb * 64 + w * 16 + lr) * NBATCH + nb) * HID + hd * 64;
#pragma unroll
    for (int td = 0; td < 4; ++td) {
      uint2 o;
      o.x = cvtpk(accO[td][0] * inv, accO[td][1] * inv);
      o.y = cvtpk(accO[td][2] * inv, accO[td][3] * inv);
      *(uint2*)&O[rowbase + td * 16 + 4 * lg] = o;
    }
  } else {
    const int hbase = (qb * Z_DIM + z) * NSPLIT + split;
    const size_t prow = (size_t)hbase * 64 + w * 16 + lr;
#pragma unroll
    for (int td = 0; td < 4; ++td)
      *(f32x4*)&Pp[prow * 64 + td * 16 + 4 * lg] = accO[td];
    if (l < 16) {
      Mp[hbase * 64 + w * 16 + lr] = m;
      Lp[hbase * 64 + w * 16 + lr] = lsum;
    }
  }
}

// ---------------- combine head split-K partials ----------------
__global__ __launch_bounds__(256)
void head_reduce(const float* __restrict__ Pp, const float* __restrict__ Mp,
                 const float* __restrict__ Lp, ushort* __restrict__ O) {
  const int z = blockIdx.x >> 1, qb = blockIdx.x & 1;
  const int tid = threadIdx.x;
  const int row = tid >> 2, cg = tid & 3;
  const int base = (qb * Z_DIM + z) * NSPLIT;

  float mm[NSPLIT], wgt[NSPLIT];
  float mx = -1e30f;
#pragma unroll
  for (int s = 0; s < NSPLIT; ++s) {
    mm[s] = Mp[(base + s) * 64 + row];
    mx = fmaxf(mx, mm[s]);
  }
  float denom = 0.f;
#pragma unroll
  for (int s = 0; s < NSPLIT; ++s) {
    wgt[s] = __expf(mm[s] - mx);
    denom += Lp[(base + s) * 64 + row] * wgt[s];
  }
  const float inv = 1.f / denom;

  const int nb = z >> 4, hd = z & 15;
  const int lseq = qb * 64 + row;
#pragma unroll
  for (int c = 0; c < 16; ++c) {
    const int col = cg * 16 + c;
    float acc = 0.f;
#pragma unroll
    for (int s = 0; s < NSPLIT; ++s)
      acc += Pp[((size_t)(base + s) * 64 + row) * 64 + col] * wgt[s];
    O[((size_t)lseq * NBATCH + nb) * HID + hd * 64 + col] = f2bf(acc * inv);
  }
}

extern "C" void kernel_launch(void* const* d_in, const int* in_sizes, int n_in,
                              void* d_out, int out_size, void* d_ws, size_t ws_size,
                              hipStream_t stream) {
  (void)in_sizes; (void)n_in; (void)out_size; (void)ws_size;
  const float* query    = (const float*)d_in[0];
  const float* q_proj   = (const float*)d_in[1];
  const float* q_bias   = (const float*)d_in[2];
  const float* k_proj   = (const float*)d_in[3];
  const float* k_bias   = (const float*)d_in[4];
  const float* v_proj   = (const float*)d_in[5];
  const float* v_bias   = (const float*)d_in[6];
  const float* out_proj = (const float*)d_in[7];
  const float* out_bias = (const float*)d_in[8];
  const int*   rnd      = (const int*)d_in[9];

  ushort* Xb  = (ushort*)d_ws;                         // [8192][1024] bf16
  ushort* Wq  = Xb + (size_t)NROWS * HID;
  ushort* Wk  = Wq + (size_t)HID * HID;
  ushort* Wv  = Wk + (size_t)HID * HID;
  ushort* Wo  = Wv + (size_t)HID * HID;
  ushort* Qb  = Wo + (size_t)HID * HID;                // [Z][L][64]
  ushort* Kb  = Qb + (size_t)Z_DIM * L_SEQ * DH;       // [Z][L][64]
  ushort* Vtb = Kb + (size_t)Z_DIM * L_SEQ * DH;       // [Z][64][L]
  float*  Pp  = (float*)(Vtb + (size_t)Z_DIM * DH * L_SEQ);  // head partials
  float*  Mp  = Pp + (size_t)2 * Z_DIM * NSPLIT * 64 * 64;
  float*  Lp  = Mp + (size_t)2 * Z_DIM * NSPLIT * 64;
  ushort* Ob  = Xb;  // alias: X dead after QKV GEMM, O written by attn
  float*  Fo  = (float*)d_out;

  cvt_multi<<<(NROWS * HID / 4 + 4 * HID * HID / 4) / 256, 256, 0, stream>>>(
      query, Xb, q_proj, Wq, k_proj, Wk, v_proj, Wv, out_proj, Wo);

  gemm_bt<0><<<1536, 256, 0, stream>>>(
      Xb, Wq, Wk, Wv, q_bias, k_bias, v_bias, Qb, Kb, Vtb, nullptr);

  attn_sparse<<<Z_DIM * 62 + 2 * Z_DIM * NSPLIT, 256, 0, stream>>>(
      Qb, Kb, Vtb, rnd, Ob, Pp, Mp, Lp);

  head_reduce<<<2 * Z_DIM, 256, 0, stream>>>(Pp, Mp, Lp, Ob);

  gemm_bt<1><<<512, 256, 0, stream>>>(
      Ob, Wo, nullptr, nullptr, out_bias, nullptr, nullptr,
      nullptr, nullptr, nullptr, Fo);
}

// Round 13
// 154.445 us; speedup vs baseline: 1.0662x; 1.0134x over previous
//
#include <hip/hip_runtime.h>
#include <stdint.h>

#define L_SEQ 4096
#define NBATCH 2
#define HID 1024
#define HEADS 16
#define DH 64
#define Z_DIM 32
#define NBLK 64
#define NROWS 8192  // L_SEQ * NBATCH
#define NSPLIT 8    // head split-K factor (8 kblocks per split)

typedef float f32x4 __attribute__((ext_vector_type(4)));
typedef short short8 __attribute__((ext_vector_type(8)));
typedef uint32_t u32x4 __attribute__((ext_vector_type(4)));

typedef const uint32_t __attribute__((address_space(1))) *gas_ptr;
typedef uint32_t __attribute__((address_space(3))) *las_ptr;

__device__ __forceinline__ ushort f2bf(float f) {
  uint32_t u = __float_as_uint(f);
  uint32_t r = (u + 0x7FFFu + ((u >> 16) & 1u)) >> 16;  // RNE
  return (ushort)r;
}

// packed f32x2 -> bf16x2 (low = a, high = b), RNE
__device__ __forceinline__ uint32_t cvtpk(float a, float b) {
  uint32_t r;
  asm("v_cvt_pk_bf16_f32 %0, %1, %2" : "=v"(r) : "v"(a), "v"(b));
  return r;
}

__device__ __forceinline__ void gload_lds16(const void* g, void* l) {
  __builtin_amdgcn_global_load_lds((gas_ptr)g, (las_ptr)l, 16, 0, 0);
}

// ---------------- fused f32 -> bf16 conversion (query + 4 weights) --------
__global__ __launch_bounds__(256)
void cvt_multi(const float* __restrict__ s0, ushort* __restrict__ d0,
               const float* __restrict__ s1, ushort* __restrict__ d1,
               const float* __restrict__ s2, ushort* __restrict__ d2,
               const float* __restrict__ s3, ushort* __restrict__ d3,
               const float* __restrict__ s4, ushort* __restrict__ d4) {
  const int i = blockIdx.x * blockDim.x + threadIdx.x;
  const int NQ = NROWS * HID / 4;          // 2097152 float4s
  const float4* src; ushort4* dst; int off;
  if (i < NQ) {
    src = (const float4*)s0; dst = (ushort4*)d0; off = i;
  } else {
    const int j = i - NQ;
    const int r = j >> 18;                  // HID*HID/4 = 2^18 per weight
    off = j & ((1 << 18) - 1);
    src = (const float4*)(r == 0 ? s1 : r == 1 ? s2 : r == 2 ? s3 : s4);
    dst = (ushort4*)(r == 0 ? d1 : r == 1 ? d2 : r == 2 ? d3 : d4);
  }
  float4 v = src[off];
  ushort4 o;
  o.x = f2bf(v.x); o.y = f2bf(v.y); o.z = f2bf(v.z); o.w = f2bf(v.w);
  dst[off] = o;
}

// ---------------- bf16 NT GEMM: C = X @ W^T + bias ----------------
// 128x128 tile, BK=32, 4 waves (2x2), 16x16x32 MFMA.
// THREE LDS buffers (48 KB), depth-2 prefetch, counted vmcnt(4), single
// barrier per K-step. 2-way-free XOR swizzle. XCD block swizzle.
// (R11 = R9 perf; kept. R8: no VGPR cap. R10: 256-wide tile regressed.)
template <int FINAL>
__global__ __launch_bounds__(256)
void gemm_bt(const ushort* __restrict__ X,
             const ushort* __restrict__ W0, const ushort* __restrict__ W1,
             const ushort* __restrict__ W2,
             const float* __restrict__ b0, const float* __restrict__ b1,
             const float* __restrict__ b2,
             ushort* __restrict__ Qo, ushort* __restrict__ Ko,
             ushort* __restrict__ Vo, float* __restrict__ Fo) {
  const int tid = threadIdx.x;
  const int w = tid >> 6, l = tid & 63;
  const int lr = l & 15, lg = l >> 4;
  const int wr = w >> 1, wc = w & 1;

  // XCD-aware bijective block swizzle (total % 8 == 0)
  const int total = FINAL ? 512 : 1536;
  const int per = total >> 3;
  const int f0 = blockIdx.x;
  const int nf = (f0 & 7) * per + (f0 >> 3);
  const int bx = nf & 7;
  const int by = (nf >> 3) & 63;
  const int zid = FINAL ? 0 : (nf >> 9);
  const int mbase = by * 128;
  const int nbase = bx * 128;

  const ushort* W = FINAL ? W0 : (zid == 0 ? W0 : (zid == 1 ? W1 : W2));
  const float*  B = FINAL ? b0 : (zid == 0 ? b0 : (zid == 1 ? b1 : b2));

  __shared__ ushort lds[3][8192];  // 48 KiB: per buf, lA (4096) | lB (4096)

  // loop-invariant swizzled k-chunk offset (shorts) within a 32-short row
  const int kch = (lg ^ ((lr >> 1) & 3)) << 3;

  f32x4 acc[4][4];
#pragma unroll
  for (int m = 0; m < 4; ++m)
#pragma unroll
    for (int n = 0; n < 4; ++n) acc[m][n] = (f32x4){0.f, 0.f, 0.f, 0.f};

  auto stage = [&](int k0, int buf) {
#pragma unroll
    for (int s = 0; s < 2; ++s) {
      const int chunk = s * 256 + tid;        // 0..511, 16B chunks
      const int row = chunk >> 2, cc = chunk & 3;
      const int scc = cc ^ ((row >> 1) & 3);  // pre-swizzled global source
      gload_lds16(X + (size_t)(mbase + row) * HID + k0 + scc * 8,
                  &lds[buf][(s * 256 + (tid & ~63)) * 8]);
      gload_lds16(W + (size_t)(nbase + row) * HID + k0 + scc * 8,
                  &lds[buf][4096 + (s * 256 + (tid & ~63)) * 8]);
    }
  };

  auto compute_tile = [&](const ushort* lA, const ushort* lB) {
    short8 af[4], bfr[4];
#pragma unroll
    for (int m = 0; m < 4; ++m)
      af[m] = *(const short8*)&lA[(wr * 64 + m * 16 + lr) * 32 + kch];
#pragma unroll
    for (int n = 0; n < 4; ++n)
      bfr[n] = *(const short8*)&lB[(wc * 64 + n * 16 + lr) * 32 + kch];
#pragma unroll
    for (int m = 0; m < 4; ++m)
#pragma unroll
      for (int n = 0; n < 4; ++n)
        acc[m][n] = __builtin_amdgcn_mfma_f32_16x16x32_bf16(af[m], bfr[n], acc[m][n], 0, 0, 0);
  };

  // ---- 3-buffer single-barrier K-loop (32 tiles of BK=32) ----
  stage(0, 0);
  stage(32, 1);
  for (int t = 0; t < 32; ++t) {
    if (t < 30) { asm volatile("s_waitcnt vmcnt(4)" ::: "memory"); }
    else        { asm volatile("s_waitcnt vmcnt(0)" ::: "memory"); }
    __builtin_amdgcn_s_barrier();  // stage(t) visible; buf (t-1)%3 free
    __builtin_amdgcn_sched_barrier(0);
    const int b = t % 3;
    compute_tile(&lds[b][0], &lds[b][4096]);
    if (t < 30) stage((t + 2) * 32, (t + 2) % 3);  // overwrite (t-1)%3
  }

  if (FINAL) {
#pragma unroll
    for (int n = 0; n < 4; ++n) {
      const int col = nbase + wc * 64 + n * 16 + lr;
      const float bias = B[col];
#pragma unroll
      for (int m = 0; m < 4; ++m)
#pragma unroll
        for (int r = 0; r < 4; ++r) {
          const int row = mbase + wr * 64 + m * 16 + 4 * lg + r;
          Fo[(size_t)row * HID + col] = acc[m][n][r] + bias;
        }
    }
    return;
  }

  float biasn[4];
#pragma unroll
  for (int n = 0; n < 4; ++n) biasn[n] = B[nbase + wc * 64 + n * 16 + lr];
  ushort* st = &lds[0][0];

  if (zid == 2) {
    // ---- V: LDS transpose -> coalesced Vt[z][d][lseq] (16B stores) ----
#pragma unroll
    for (int nb2 = 0; nb2 < 2; ++nb2) {
#pragma unroll
      for (int ch = 0; ch < 2; ++ch) {
        __syncthreads();
        if (wc == ch) {
#pragma unroll
          for (int m = 0; m < 4; ++m)
#pragma unroll
            for (int n = 0; n < 4; ++n)
#pragma unroll
              for (int rr = 0; rr < 2; ++rr) {
                const int r = nb2 + 2 * rr;
                st[(n * 16 + lr) * 72 + wr * 32 + m * 8 + 2 * lg + rr] =
                    f2bf(acc[m][n][r] + biasn[n]);
              }
        }
        __syncthreads();
        const int zz = nb2 * HEADS + (nbase >> 6) + ch;
#pragma unroll
        for (int it = 0; it < 2; ++it) {
          const int c = it * 256 + tid;          // 0..511
          const int colI = c >> 3, ls0 = (c & 7) * 8;
          const short8 v = *(const short8*)&st[colI * 72 + ls0];
          *(short8*)&Vo[((size_t)zz * DH + colI) * L_SEQ + (mbase >> 1) + ls0] = v;
        }
      }
    }
  } else {
    // ---- Q/K: LDS stage -> coalesced Out[z][lseq][d] (16B stores) ----
    ushort* Out = (zid == 0) ? Qo : Ko;
    const float sc = (zid == 0) ? 0.125f : 1.f;
#pragma unroll
    for (int nbp = 0; nbp < 2; ++nbp) {
#pragma unroll
      for (int hh = 0; hh < 2; ++hh) {
        __syncthreads();
        if (wc == hh) {
#pragma unroll
          for (int m = 0; m < 4; ++m)
#pragma unroll
            for (int n = 0; n < 4; ++n)
#pragma unroll
              for (int rr = 0; rr < 2; ++rr) {
                const int r = nbp + 2 * rr;
                st[(wr * 32 + m * 8 + 2 * lg + rr) * 72 + n * 16 + lr] =
                    f2bf((acc[m][n][r] + biasn[n]) * sc);
              }
        }
        __syncthreads();
        const int zz = nbp * HEADS + (nbase >> 6) + hh;
#pragma unroll
        for (int it = 0; it < 2; ++it) {
          const int c = it * 256 + tid;          // 0..511
          const int lr2 = c >> 3, cc8 = c & 7;
          const short8 v = *(const short8*)&st[lr2 * 72 + cc8 * 8];
          *(short8*)&Out[((size_t)zz * L_SEQ + (mbase >> 1) + lr2) * DH + cc8 * 8] = v;
        }
      }
    }
  }
}

// ---------------- block-sparse attention (R7 core + XCD z-affinity) -------
// Block remap: all blocks of one z land on one XCD (bid%8) so z's ~1MB K/V
// set stays L2-resident (4 z's = 4MB = one XCD L2). Serial slots, single-
// buffer Kl/Vl staging via global_load_lds + row-XOR swizzle; swapped math
// S = mfma(K, Q^T); lane-local softmax; P via cvt_pk -> per-wave LDS slab;
// PV: O^T = mfma(V^T, P^T). setprio(1) around MFMA clusters (T5, m191).
__global__ __launch_bounds__(256)
void attn_sparse(const ushort* __restrict__ Q, const ushort* __restrict__ K,
                 const ushort* __restrict__ Vt, const int* __restrict__ rnd,
                 ushort* __restrict__ O,
                 float* __restrict__ Pp, float* __restrict__ Mp,
                 float* __restrict__ Lp) {
  const int bid = blockIdx.x;
  int z, qb, split = 0;
  bool head;
  if (bid < Z_DIM * 62) {
    // z = (bid&7)*4 + (bid>>3)/62  -> all 62 qb-blocks of z share bid%8 (XCD)
    const int x = bid & 7, k = bid >> 3;
    z = x * 4 + k / 62;
    qb = 2 + k % 62;
    head = false;
  } else {
    const int t = bid - Z_DIM * 62;          // 0..511
    const int x = t & 7, j = t >> 3;         // j: 0..63
    z = x * 4 + (j & 3);
    const int s2 = j >> 2;                   // 0..15
    qb = s2 & 1;
    split = s2 >> 1;
    head = true;
  }
  const int tid = threadIdx.x;
  const int w = tid >> 6, l = tid & 63;
  const int lr = l & 15, lg = l >> 4;

  __shared__ ushort Kl[64 * 64];
  __shared__ ushort Vl[64 * 64];
  __shared__ uint32_t P2[4][16 * 36];  // per-wave P^T: [q=lr][kp], pitch 36 u32

  // B-operand Q^T fragments: lane holds Q[q = lr][d = lg*8 + j]
  const ushort* Qrow = Q + ((size_t)z * L_SEQ + qb * 64 + w * 16 + lr) * DH;
  const short8 bq0 = *(const short8*)(Qrow + lg * 8);
  const short8 bq1 = *(const short8*)(Qrow + 32 + lg * 8);

  float m = -1e30f, lsum = 0.f;
  f32x4 accO[4];  // accO[td][r] = O[q=lr][d = td*16 + 4*lg + r]
#pragma unroll
  for (int td = 0; td < 4; ++td) accO[td] = (f32x4){0.f, 0.f, 0.f, 0.f};

  const int nslot = head ? 8 : 7;
  int sk[3] = {0, 0, 0}, sv[3] = {0, 0, 0}, rk0 = 0, rk1 = 0;
  if (!head) {
    const int i = qb - 2;
    rk0 = rnd[2 * i]; rk1 = rnd[2 * i + 1];
    if (qb < NBLK - 1) {
      sk[0] = qb - 1; sk[1] = qb; sk[2] = qb + 1;
      sv[0] = qb - 1; sv[1] = qb; sv[2] = qb + 1;
    } else {  // bottom row: K = {ZERO, 62, 63}, V = {62, 63, ZERO}
      sk[0] = -1; sk[1] = NBLK - 2; sk[2] = NBLK - 1;
      sv[0] = NBLK - 2; sv[1] = NBLK - 1; sv[2] = -1;
    }
  }

  for (int slot = 0; slot < nslot; ++slot) {
    int ki, vi;
    if (head) { ki = split * 8 + slot; vi = ki; }
    else if (slot < 2) { ki = slot; vi = slot; }
    else if (slot < 5) { ki = sk[slot - 2]; vi = sv[slot - 2]; }
    else { ki = (slot == 5) ? rk0 : rk1; vi = ki; }

    if (slot) __syncthreads();  // all waves done reading Kl/Vl
#pragma unroll
    for (int s = 0; s < 2; ++s) {
      const int chunk = s * 256 + tid;
      const int row = chunk >> 3, cc = chunk & 7;
      const int scc = cc ^ (row & 7);  // pre-swizzled global source
      if (ki >= 0)
        gload_lds16(K + ((size_t)z * L_SEQ + ki * 64 + row) * DH + scc * 8,
                    &Kl[(s * 256 + (tid & ~63)) * 8]);
      if (vi >= 0)
        gload_lds16(Vt + ((size_t)z * DH + row) * L_SEQ + vi * 64 + scc * 8,
                    &Vl[(s * 256 + (tid & ~63)) * 8]);
    }
    __syncthreads();

    // ---- QK^T (swapped): sc[t][r] = S[key = t*16+4*lg+r][q = lr] ----
    f32x4 sc[4];
    if (ki >= 0) {
      __builtin_amdgcn_s_setprio(1);
#pragma unroll
      for (int t = 0; t < 4; ++t) {
        const int row = t * 16 + lr;
        const short8 a0 = *(const short8*)&Kl[row * 64 + ((lg ^ (row & 7)) << 3)];
        const short8 a1 = *(const short8*)&Kl[row * 64 + (((4 + lg) ^ (row & 7)) << 3)];
        f32x4 zz = (f32x4){0.f, 0.f, 0.f, 0.f};
        sc[t] = __builtin_amdgcn_mfma_f32_16x16x32_bf16(a0, bq0, zz, 0, 0, 0);
        sc[t] = __builtin_amdgcn_mfma_f32_16x16x32_bf16(a1, bq1, sc[t], 0, 0, 0);
      }
      __builtin_amdgcn_s_setprio(0);
    } else {
#pragma unroll
      for (int t = 0; t < 4; ++t) sc[t] = (f32x4){0.f, 0.f, 0.f, 0.f};
    }

    // ---- online softmax over keys (16 regs x 4 lg-groups) ----
    float sm = sc[0][0];
#pragma unroll
    for (int t = 0; t < 4; ++t)
#pragma unroll
      for (int r = 0; r < 4; ++r) sm = fmaxf(sm, sc[t][r]);
    sm = fmaxf(sm, __shfl_xor(sm, 16));
    sm = fmaxf(sm, __shfl_xor(sm, 32));
    const float mn = fmaxf(m, sm);
    const float scale = __expf(m - mn);
    m = mn;
    lsum *= scale;
#pragma unroll
    for (int td = 0; td < 4; ++td)
#pragma unroll
      for (int r = 0; r < 4; ++r) accO[td][r] *= scale;
    float psum = 0.f;
#pragma unroll
    for (int t = 0; t < 4; ++t)
#pragma unroll
      for (int r = 0; r < 4; ++r) {
        const float p = __expf(sc[t][r] - mn);
        sc[t][r] = p;
        psum += p;
      }
    psum += __shfl_xor(psum, 16);
    psum += __shfl_xor(psum, 32);
    lsum += psum;

    if (vi >= 0) {
      // P -> bf16x2 u32s -> per-wave LDS [q=lr][kp], kp = key/2
      uint32_t* Pq = &P2[w][0];
#pragma unroll
      for (int t = 0; t < 4; ++t) {
        Pq[lr * 36 + t * 8 + 2 * lg + 0] = cvtpk(sc[t][0], sc[t][1]);
        Pq[lr * 36 + t * 8 + 2 * lg + 1] = cvtpk(sc[t][2], sc[t][3]);
      }
      // B-frags: lane holds P^T[key = f*32 + lg*8 + j][q = lr]
      union { u32x4 u; short8 s8; } pb0, pb1;
      pb0.u = *(const u32x4*)&Pq[lr * 36 + lg * 4];
      pb1.u = *(const u32x4*)&Pq[lr * 36 + 16 + lg * 4];
      __builtin_amdgcn_s_setprio(1);
#pragma unroll
      for (int td = 0; td < 4; ++td) {
        const int row = td * 16 + lr;
        const short8 av0 = *(const short8*)&Vl[row * 64 + ((lg ^ (row & 7)) << 3)];
        const short8 av1 = *(const short8*)&Vl[row * 64 + (((4 + lg) ^ (row & 7)) << 3)];
        accO[td] = __builtin_amdgcn_mfma_f32_16x16x32_bf16(av0, pb0.s8, accO[td], 0, 0, 0);
        accO[td] = __builtin_amdgcn_mfma_f32_16x16x32_bf16(av1, pb1.s8, accO[td], 0, 0, 0);
      }
      __builtin_amdgcn_s_setprio(0);
    }
  }

  if (!head) {
    const float inv = 1.f / lsum;
    const int nb = z >> 4, hd = z & 15;
    const size_t rowbase =
        ((size_t)(qb * 64 + w * 16 + lr) * NBATCH + nb) * HID + hd * 64;
#pragma unroll
    for (int td = 0; td < 4; ++td) {
      uint2 o;
      o.x = cvtpk(accO[td][0] * inv, accO[td][1] * inv);
      o.y = cvtpk(accO[td][2] * inv, accO[td][3] * inv);
      *(uint2*)&O[rowbase + td * 16 + 4 * lg] = o;
    }
  } else {
    const int hbase = (qb * Z_DIM + z) * NSPLIT + split;
    const size_t prow = (size_t)hbase * 64 + w * 16 + lr;
#pragma unroll
    for (int td = 0; td < 4; ++td)
      *(f32x4*)&Pp[prow * 64 + td * 16 + 4 * lg] = accO[td];
    if (l < 16) {
      Mp[hbase * 64 + w * 16 + lr] = m;
      Lp[hbase * 64 + w * 16 + lr] = lsum;
    }
  }
}

// ---------------- combine head split-K partials ----------------
__global__ __launch_bounds__(256)
void head_reduce(const float* __restrict__ Pp, const float* __restrict__ Mp,
                 const float* __restrict__ Lp, ushort* __restrict__ O) {
  const int z = blockIdx.x >> 1, qb = blockIdx.x & 1;
  const int tid = threadIdx.x;
  const int row = tid >> 2, cg = tid & 3;
  const int base = (qb * Z_DIM + z) * NSPLIT;

  float mm[NSPLIT], wgt[NSPLIT];
  float mx = -1e30f;
#pragma unroll
  for (int s = 0; s < NSPLIT; ++s) {
    mm[s] = Mp[(base + s) * 64 + row];
    mx = fmaxf(mx, mm[s]);
  }
  float denom = 0.f;
#pragma unroll
  for (int s = 0; s < NSPLIT; ++s) {
    wgt[s] = __expf(mm[s] - mx);
    denom += Lp[(base + s) * 64 + row] * wgt[s];
  }
  const float inv = 1.f / denom;

  const int nb = z >> 4, hd = z & 15;
  const int lseq = qb * 64 + row;
#pragma unroll
  for (int c = 0; c < 16; ++c) {
    const int col = cg * 16 + c;
    float acc = 0.f;
#pragma unroll
    for (int s = 0; s < NSPLIT; ++s)
      acc += Pp[((size_t)(base + s) * 64 + row) * 64 + col] * wgt[s];
    O[((size_t)lseq * NBATCH + nb) * HID + hd * 64 + col] = f2bf(acc * inv);
  }
}

extern "C" void kernel_launch(void* const* d_in, const int* in_sizes, int n_in,
                              void* d_out, int out_size, void* d_ws, size_t ws_size,
                              hipStream_t stream) {
  (void)in_sizes; (void)n_in; (void)out_size; (void)ws_size;
  const float* query    = (const float*)d_in[0];
  const float* q_proj   = (const float*)d_in[1];
  const float* q_bias   = (const float*)d_in[2];
  const float* k_proj   = (const float*)d_in[3];
  const float* k_bias   = (const float*)d_in[4];
  const float* v_proj   = (const float*)d_in[5];
  const float* v_bias   = (const float*)d_in[6];
  const float* out_proj = (const float*)d_in[7];
  const float* out_bias = (const float*)d_in[8];
  const int*   rnd      = (const int*)d_in[9];

  ushort* Xb  = (ushort*)d_ws;                         // [8192][1024] bf16
  ushort* Wq  = Xb + (size_t)NROWS * HID;
  ushort* Wk  = Wq + (size_t)HID * HID;
  ushort* Wv  = Wk + (size_t)HID * HID;
  ushort* Wo  = Wv + (size_t)HID * HID;
  ushort* Qb  = Wo + (size_t)HID * HID;                // [Z][L][64]
  ushort* Kb  = Qb + (size_t)Z_DIM * L_SEQ * DH;       // [Z][L][64]
  ushort* Vtb = Kb + (size_t)Z_DIM * L_SEQ * DH;       // [Z][64][L]
  float*  Pp  = (float*)(Vtb + (size_t)Z_DIM * DH * L_SEQ);  // head partials
  float*  Mp  = Pp + (size_t)2 * Z_DIM * NSPLIT * 64 * 64;
  float*  Lp  = Mp + (size_t)2 * Z_DIM * NSPLIT * 64;
  ushort* Ob  = Xb;  // alias: X dead after QKV GEMM, O written by attn
  float*  Fo  = (float*)d_out;

  cvt_multi<<<(NROWS * HID / 4 + 4 * HID * HID / 4) / 256, 256, 0, stream>>>(
      query, Xb, q_proj, Wq, k_proj, Wk, v_proj, Wv, out_proj, Wo);

  gemm_bt<0><<<1536, 256, 0, stream>>>(
      Xb, Wq, Wk, Wv, q_bias, k_bias, v_bias, Qb, Kb, Vtb, nullptr);

  attn_sparse<<<Z_DIM * 62 + 2 * Z_DIM * NSPLIT, 256, 0, stream>>>(
      Qb, Kb, Vtb, rnd, Ob, Pp, Mp, Lp);

  head_reduce<<<2 * Z_DIM, 256, 0, stream>>>(Pp, Mp, Lp, Ob);

  gemm_bt<1><<<512, 256, 0, stream>>>(
      Ob, Wo, nullptr, nullptr, out_bias, nullptr, nullptr,
      nullptr, nullptr, nullptr, Fo);
}